// Round 1
// baseline (3080.081 us; speedup 1.0000x reference)
//
#include <hip/hip_runtime.h>

#define N_NODES 100000
#define N_EDGES 800000
#define N_IN    256
#define N_H     128

// ---------------- GEMM: h[n][j] = sum_k x[n][k] * W[k][j] (fp32) -------------
// Block 256 threads: tx = t&15 (n-quads), ty = t>>4 (m-quads).
// Tile: BM=64 rows x full N_H=128, BK=32. Each thread: 4 rows x 8 cols.
// xT staged transposed [k][row] (stride 68: float4-aligned, <=2-way banks).
#define BM 64
#define BK 32
#define XT_S 68

__global__ __launch_bounds__(256) void gemm_kernel(const float* __restrict__ x,
                                                   const float* __restrict__ W,
                                                   float* __restrict__ h) {
    __shared__ float xT[BK * XT_S];   // [k][row], padded
    __shared__ float wl[BK * N_H];    // [k][n]
    const int t  = threadIdx.x;
    const int m0 = blockIdx.x * BM;
    const int tx = t & 15;
    const int ty = t >> 4;

    float acc0[4][4];  // rows ty*4+r, cols tx*4+c
    float acc1[4][4];  // rows ty*4+r, cols 64+tx*4+c
#pragma unroll
    for (int r = 0; r < 4; ++r)
#pragma unroll
        for (int c = 0; c < 4; ++c) { acc0[r][c] = 0.f; acc1[r][c] = 0.f; }

    for (int kk = 0; kk < N_IN; kk += BK) {
        // stage x tile: 64 rows x 32 k -> xT[k][row]; 512 float4, 2/thread.
        // lanes -> consecutive rows => conflict-free LDS writes; global reads
        // are 16B/lane at 1KB stride but all 4 waves share lines via L1.
#pragma unroll
        for (int i = 0; i < 2; ++i) {
            int f   = t + i * 256;
            int row = f & 63;
            int kp  = (f >> 6) * 4;
            int gr  = m0 + row;
            float4 v = make_float4(0.f, 0.f, 0.f, 0.f);
            if (gr < N_NODES)
                v = *(const float4*)(x + (size_t)gr * N_IN + kk + kp);
            xT[(kp + 0) * XT_S + row] = v.x;
            xT[(kp + 1) * XT_S + row] = v.y;
            xT[(kp + 2) * XT_S + row] = v.z;
            xT[(kp + 3) * XT_S + row] = v.w;
        }
        // stage W tile: 32 k x 128 n = 1024 float4, 4/thread, coalesced.
#pragma unroll
        for (int i = 0; i < 4; ++i) {
            int f  = t + i * 256;
            int k  = f >> 5;
            int np = (f & 31) * 4;
            *(float4*)(wl + k * N_H + np) =
                *(const float4*)(W + (size_t)(kk + k) * N_H + np);
        }
        __syncthreads();
#pragma unroll
        for (int k = 0; k < BK; ++k) {
            float4 a  = *(const float4*)(xT + k * XT_S + ty * 4);
            float4 b0 = *(const float4*)(wl + k * N_H + tx * 4);
            float4 b1 = *(const float4*)(wl + k * N_H + 64 + tx * 4);
            float av[4]  = {a.x, a.y, a.z, a.w};
            float bv0[4] = {b0.x, b0.y, b0.z, b0.w};
            float bv1[4] = {b1.x, b1.y, b1.z, b1.w};
#pragma unroll
            for (int r = 0; r < 4; ++r)
#pragma unroll
                for (int c = 0; c < 4; ++c) {
                    acc0[r][c] += av[r] * bv0[c];
                    acc1[r][c] += av[r] * bv1[c];
                }
        }
        __syncthreads();
    }
#pragma unroll
    for (int r = 0; r < 4; ++r) {
        int gr = m0 + ty * 4 + r;
        if (gr < N_NODES) {
            *(float4*)(h + (size_t)gr * N_H + tx * 4) =
                make_float4(acc0[r][0], acc0[r][1], acc0[r][2], acc0[r][3]);
            *(float4*)(h + (size_t)gr * N_H + 64 + tx * 4) =
                make_float4(acc1[r][0], acc1[r][1], acc1[r][2], acc1[r][3]);
        }
    }
}

// ---------------- SPMM: agg[row_e] += w_e * h[col_e]  (atomic) ---------------
// 32 lanes per edge, float4 gather (512B contiguous per edge), 8 edges/block.
__global__ __launch_bounds__(256) void spmm_kernel(const int* __restrict__ ei,
                                                   const float* __restrict__ ew,
                                                   const float* __restrict__ h,
                                                   float* __restrict__ agg) {
    const int t  = threadIdx.x;
    const int e  = blockIdx.x * 8 + (t >> 5);
    const int j4 = (t & 31) * 4;
    const int row = ei[e];             // edge_index[0][e]
    const int col = ei[N_EDGES + e];   // edge_index[1][e]
    const float w = ew[e];
    float4 hv = *(const float4*)(h + (size_t)col * N_H + j4);
    float* dst = agg + (size_t)row * N_H + j4;
    atomicAdd(dst + 0, w * hv.x);
    atomicAdd(dst + 1, w * hv.y);
    atomicAdd(dst + 2, w * hv.z);
    atomicAdd(dst + 3, w * hv.w);
}

// ---------------- epilogue: z[i] = dot(prelu(agg[i]+bias), w_sum) + b_sum ----
__global__ __launch_bounds__(256) void epilogue_kernel(const float* __restrict__ agg,
                                                       const float* __restrict__ gcn_bias,
                                                       const float* __restrict__ prelu_a,
                                                       const float* __restrict__ wsum,
                                                       float* __restrict__ zout) {
    const int wave = threadIdx.x >> 6;
    const int lane = threadIdx.x & 63;
    const int node = blockIdx.x * 4 + wave;
    if (node >= N_NODES) return;
    const float a = prelu_a[0];
    float v0 = agg[(size_t)node * N_H + lane]      + gcn_bias[lane];
    float v1 = agg[(size_t)node * N_H + 64 + lane] + gcn_bias[64 + lane];
    v0 = (v0 >= 0.f) ? v0 : a * v0;
    v1 = (v1 >= 0.f) ? v1 : a * v1;
    float s = v0 * wsum[lane] + v1 * wsum[64 + lane];
#pragma unroll
    for (int off = 32; off; off >>= 1) s += __shfl_down(s, off, 64);
    if (lane == 0) zout[node] = s + wsum[128];   // wsum[128] = b_sum
}

// ---------------- tiny precompute: w_sum[j] = sum_o lin_W[j][o]; b_sum -------
__global__ void wsum_kernel(const float* __restrict__ linW,
                            const float* __restrict__ linb,
                            float* __restrict__ wsum) {
    const int j = threadIdx.x;
    if (j < N_H) {
        float s = 0.f;
        for (int o = 0; o < N_H; ++o) s += linW[j * N_H + o];
        wsum[j] = s;
    }
    if (j == N_H) {
        float s = 0.f;
        for (int o = 0; o < N_H; ++o) s += linb[o];
        wsum[N_H] = s;
    }
}

extern "C" void kernel_launch(void* const* d_in, const int* in_sizes, int n_in,
                              void* d_out, int out_size, void* d_ws, size_t ws_size,
                              hipStream_t stream) {
    const float* x1 = (const float*)d_in[0];
    const float* x2 = (const float*)d_in[1];
    const int*   ei = (const int*)d_in[2];
    const float* ew = (const float*)d_in[3];
    const float* Wg = (const float*)d_in[4];
    const float* gb = (const float*)d_in[5];
    const float* pa = (const float*)d_in[6];
    const float* lW = (const float*)d_in[7];
    const float* lb = (const float*)d_in[8];
    float* zout = (float*)d_out;

    const size_t HBYTES = (size_t)N_NODES * N_H * sizeof(float);  // 51.2 MB
    char* ws    = (char*)d_ws;
    float* h    = (float*)(ws);
    float* agg  = (float*)(ws + HBYTES);
    float* wsum = (float*)(ws + 2 * HBYTES);

    wsum_kernel<<<1, 256, 0, stream>>>(lW, lb, wsum);

    const int gemm_grid = (N_NODES + BM - 1) / BM;   // 1563
    for (int b = 0; b < 2; ++b) {
        const float* x = b ? x2 : x1;
        hipMemsetAsync(agg, 0, HBYTES, stream);
        gemm_kernel<<<gemm_grid, 256, 0, stream>>>(x, Wg, h);
        spmm_kernel<<<N_EDGES / 8, 256, 0, stream>>>(ei, ew, h, agg);
        epilogue_kernel<<<(N_NODES + 3) / 4, 256, 0, stream>>>(
            agg, gb, pa, wsum, zout + (size_t)b * N_NODES);
    }
}

// Round 2
// 584.341 us; speedup vs baseline: 5.2710x; 5.2710x over previous
//
#include <hip/hip_runtime.h>

#define N_NODES 100000
#define N_EDGES 800000
#define N_IN    256
#define N_H     128

// ---------------- GEMM: h[n][j] = sum_k x[n][k] * W[k][j] (fp32) -------------
#define BM 64
#define BK 32
#define XT_S 68

__global__ __launch_bounds__(256) void gemm_kernel(const float* __restrict__ x,
                                                   const float* __restrict__ W,
                                                   float* __restrict__ h) {
    __shared__ float xT[BK * XT_S];   // [k][row], padded
    __shared__ float wl[BK * N_H];    // [k][n]
    const int t  = threadIdx.x;
    const int m0 = blockIdx.x * BM;
    const int tx = t & 15;
    const int ty = t >> 4;

    float acc0[4][4];
    float acc1[4][4];
#pragma unroll
    for (int r = 0; r < 4; ++r)
#pragma unroll
        for (int c = 0; c < 4; ++c) { acc0[r][c] = 0.f; acc1[r][c] = 0.f; }

    for (int kk = 0; kk < N_IN; kk += BK) {
#pragma unroll
        for (int i = 0; i < 2; ++i) {
            int f   = t + i * 256;
            int row = f & 63;
            int kp  = (f >> 6) * 4;
            int gr  = m0 + row;
            float4 v = make_float4(0.f, 0.f, 0.f, 0.f);
            if (gr < N_NODES)
                v = *(const float4*)(x + (size_t)gr * N_IN + kk + kp);
            xT[(kp + 0) * XT_S + row] = v.x;
            xT[(kp + 1) * XT_S + row] = v.y;
            xT[(kp + 2) * XT_S + row] = v.z;
            xT[(kp + 3) * XT_S + row] = v.w;
        }
#pragma unroll
        for (int i = 0; i < 4; ++i) {
            int f  = t + i * 256;
            int k  = f >> 5;
            int np = (f & 31) * 4;
            *(float4*)(wl + k * N_H + np) =
                *(const float4*)(W + (size_t)(kk + k) * N_H + np);
        }
        __syncthreads();
#pragma unroll
        for (int k = 0; k < BK; ++k) {
            float4 a  = *(const float4*)(xT + k * XT_S + ty * 4);
            float4 b0 = *(const float4*)(wl + k * N_H + tx * 4);
            float4 b1 = *(const float4*)(wl + k * N_H + 64 + tx * 4);
            float av[4]  = {a.x, a.y, a.z, a.w};
            float bv0[4] = {b0.x, b0.y, b0.z, b0.w};
            float bv1[4] = {b1.x, b1.y, b1.z, b1.w};
#pragma unroll
            for (int r = 0; r < 4; ++r)
#pragma unroll
                for (int c = 0; c < 4; ++c) {
                    acc0[r][c] += av[r] * bv0[c];
                    acc1[r][c] += av[r] * bv1[c];
                }
        }
        __syncthreads();
    }
#pragma unroll
    for (int r = 0; r < 4; ++r) {
        int gr = m0 + ty * 4 + r;
        if (gr < N_NODES) {
            *(float4*)(h + (size_t)gr * N_H + tx * 4) =
                make_float4(acc0[r][0], acc0[r][1], acc0[r][2], acc0[r][3]);
            *(float4*)(h + (size_t)gr * N_H + 64 + tx * 4) =
                make_float4(acc1[r][0], acc1[r][1], acc1[r][2], acc1[r][3]);
        }
    }
}

// ---------------- CSR build: histogram -> scan -> scatter --------------------
__global__ __launch_bounds__(256) void hist_kernel(const int* __restrict__ ei,
                                                   int* __restrict__ deg) {
    int e = blockIdx.x * 256 + threadIdx.x;
    if (e < N_EDGES) atomicAdd(deg + ei[e], 1);
}

// block-level exclusive scan, 256/block; writes partials + block sums
__global__ __launch_bounds__(256) void scan1_kernel(const int* __restrict__ deg,
                                                    int* __restrict__ part,
                                                    int* __restrict__ bsum) {
    __shared__ int s[256];
    int g = blockIdx.x * 256 + threadIdx.x;
    int v = (g < N_NODES) ? deg[g] : 0;
    s[threadIdx.x] = v;
    __syncthreads();
#pragma unroll
    for (int off = 1; off < 256; off <<= 1) {
        int t = (threadIdx.x >= off) ? s[threadIdx.x - off] : 0;
        __syncthreads();
        s[threadIdx.x] += t;
        __syncthreads();
    }
    if (g < N_NODES) part[g] = s[threadIdx.x] - v;   // exclusive
    if (threadIdx.x == 255) bsum[blockIdx.x] = s[255];
}

#define NBLK_SCAN 391  // ceil(100000/256)
__global__ void scan2_kernel(int* __restrict__ bsum) {
    __shared__ int s[512];
    int v = (threadIdx.x < NBLK_SCAN) ? bsum[threadIdx.x] : 0;
    s[threadIdx.x] = v;
    __syncthreads();
#pragma unroll
    for (int off = 1; off < 512; off <<= 1) {
        int t = (threadIdx.x >= off) ? s[threadIdx.x - off] : 0;
        __syncthreads();
        s[threadIdx.x] += t;
        __syncthreads();
    }
    if (threadIdx.x < NBLK_SCAN) bsum[threadIdx.x] = s[threadIdx.x] - v;  // exclusive
}

__global__ __launch_bounds__(256) void scan3_kernel(const int* __restrict__ part,
                                                    const int* __restrict__ bsum,
                                                    int* __restrict__ off,
                                                    int* __restrict__ cursor) {
    int g = blockIdx.x * 256 + threadIdx.x;
    if (g < N_NODES) {
        int o = part[g] + bsum[blockIdx.x];
        off[g] = o;
        cursor[g] = o;
    }
    if (g == 0) off[N_NODES] = N_EDGES;
}

__global__ __launch_bounds__(256) void scatter_kernel(const int* __restrict__ ei,
                                                      const float* __restrict__ ew,
                                                      int* __restrict__ cursor,
                                                      int* __restrict__ scol,
                                                      float* __restrict__ sw) {
    int e = blockIdx.x * 256 + threadIdx.x;
    if (e >= N_EDGES) return;
    int row = ei[e];
    int pos = atomicAdd(cursor + row, 1);
    scol[pos] = ei[N_EDGES + e];
    sw[pos]   = ew[e];
}

// ------- fused segment-sum SPMM + bias + PReLU + wsum-dot + reduce -----------
// one 64-lane wave per node; lane covers features (lane, lane+64); no atomics.
__global__ __launch_bounds__(256) void gcn_seg_kernel(const int* __restrict__ off,
                                                      const int* __restrict__ scol,
                                                      const float* __restrict__ sw,
                                                      const float* __restrict__ h,
                                                      const float* __restrict__ gcn_bias,
                                                      const float* __restrict__ prelu_a,
                                                      const float* __restrict__ wsum,
                                                      float* __restrict__ zout) {
    const int wave = threadIdx.x >> 6;
    const int lane = threadIdx.x & 63;
    const int node = blockIdx.x * 4 + wave;
    if (node >= N_NODES) return;
    const int s = off[node];
    const int e = off[node + 1];
    float a0 = 0.f, a1 = 0.f;
    int i = s;
    for (; i + 1 < e; i += 2) {   // 2-edge unroll: two gathers in flight
        int   c0 = scol[i],  c1 = scol[i + 1];
        float w0 = sw[i],    w1 = sw[i + 1];
        const float* p0 = h + (size_t)c0 * N_H;
        const float* p1 = h + (size_t)c1 * N_H;
        float h00 = p0[lane], h01 = p0[64 + lane];
        float h10 = p1[lane], h11 = p1[64 + lane];
        a0 += w0 * h00 + w1 * h10;
        a1 += w0 * h01 + w1 * h11;
    }
    if (i < e) {
        int c = scol[i]; float w = sw[i];
        const float* p = h + (size_t)c * N_H;
        a0 += w * p[lane];
        a1 += w * p[64 + lane];
    }
    const float alpha = prelu_a[0];
    float v0 = a0 + gcn_bias[lane];
    float v1 = a1 + gcn_bias[64 + lane];
    v0 = (v0 >= 0.f) ? v0 : alpha * v0;
    v1 = (v1 >= 0.f) ? v1 : alpha * v1;
    float sres = v0 * wsum[lane] + v1 * wsum[64 + lane];
#pragma unroll
    for (int o = 32; o; o >>= 1) sres += __shfl_down(sres, o, 64);
    if (lane == 0) zout[node] = sres + wsum[128];   // wsum[128] = b_sum
}

// ---------------- tiny precompute: w_sum[j] = sum_o lin_W[j][o]; b_sum -------
__global__ void wsum_kernel(const float* __restrict__ linW,
                            const float* __restrict__ linb,
                            float* __restrict__ wsum) {
    const int j = threadIdx.x;
    if (j < N_H) {
        float s = 0.f;
        for (int o = 0; o < N_H; ++o) s += linW[j * N_H + o];
        wsum[j] = s;
    }
    if (j == N_H) {
        float s = 0.f;
        for (int o = 0; o < N_H; ++o) s += linb[o];
        wsum[N_H] = s;
    }
}

extern "C" void kernel_launch(void* const* d_in, const int* in_sizes, int n_in,
                              void* d_out, int out_size, void* d_ws, size_t ws_size,
                              hipStream_t stream) {
    const float* x1 = (const float*)d_in[0];
    const float* x2 = (const float*)d_in[1];
    const int*   ei = (const int*)d_in[2];
    const float* ew = (const float*)d_in[3];
    const float* Wg = (const float*)d_in[4];
    const float* gb = (const float*)d_in[5];
    const float* pa = (const float*)d_in[6];
    const float* lW = (const float*)d_in[7];
    const float* lb = (const float*)d_in[8];
    float* zout = (float*)d_out;

    // ws layout (element counts; all 512B-aligned by construction)
    float* h      = (float*)d_ws;                       // 12,800,000 f
    int*   scol   = (int*)(h + 12800000);               //    800,000 i
    float* sw     = (float*)(scol + 800000);            //    800,000 f
    int*   deg    = (int*)(sw + 800000);                //    100,096 i
    int*   part   = deg + 100096;                       //    100,096 i
    int*   off    = part + 100096;                      //    100,096 i (uses 100001)
    int*   cursor = off + 100096;                       //    100,096 i
    int*   bsum   = cursor + 100096;                    //        512 i
    float* wsum   = (float*)(bsum + 512);               //        129 f
    // total ~58.6 MB < previous 102.4 MB footprint

    wsum_kernel<<<1, 256, 0, stream>>>(lW, lb, wsum);

    // ---- CSR build (edge_index constant; rebuilt every call for capture) ----
    hipMemsetAsync(deg, 0, (size_t)N_NODES * sizeof(int), stream);
    hist_kernel<<<(N_EDGES + 255) / 256, 256, 0, stream>>>(ei, deg);
    scan1_kernel<<<NBLK_SCAN, 256, 0, stream>>>(deg, part, bsum);
    scan2_kernel<<<1, 512, 0, stream>>>(bsum);
    scan3_kernel<<<NBLK_SCAN, 256, 0, stream>>>(part, bsum, off, cursor);
    scatter_kernel<<<(N_EDGES + 255) / 256, 256, 0, stream>>>(ei, ew, cursor, scol, sw);

    const int gemm_grid = (N_NODES + BM - 1) / BM;   // 1563
    const int seg_grid  = (N_NODES + 3) / 4;         // 25000
    for (int b = 0; b < 2; ++b) {
        const float* x = b ? x2 : x1;
        gemm_kernel<<<gemm_grid, 256, 0, stream>>>(x, Wg, h);
        gcn_seg_kernel<<<seg_grid, 256, 0, stream>>>(off, scol, sw, h, gb, pa, wsum,
                                                     zout + (size_t)b * N_NODES);
    }
}

// Round 3
// 467.187 us; speedup vs baseline: 6.5928x; 1.2508x over previous
//
#include <hip/hip_runtime.h>

#define N_NODES 100000
#define N_EDGES 800000
#define N_IN    256
#define N_H     128
#define M_TOT   (2 * N_NODES)   // 200000 = 3125 * 64, and 16 | 100000

typedef __bf16 bfx8 __attribute__((ext_vector_type(8)));
typedef unsigned short u16x8 __attribute__((ext_vector_type(8)));
typedef float fx4 __attribute__((ext_vector_type(4)));

__device__ inline unsigned short f2bf(float f) {
    union { float f; unsigned u; } v; v.f = f;
    return (unsigned short)((v.u + 0x7FFF + ((v.u >> 16) & 1)) >> 16);  // RNE
}
__device__ inline float bf2f(unsigned short s) {
    union { unsigned u; float f; } v; v.u = ((unsigned)s) << 16;
    return v.f;
}

// ---------------- fused bf16-MFMA GEMM, both branches --------------------
// h[r][j] = sum_k x[r][k] * W[k][j]; r in [0,200000) covers x1 then x2.
// Block: 4 waves x 16 rows = 64 rows, full N_H=128 per wave.
// W^T (bf16 [n][k]) staged whole in LDS (stride 264: 16B-aligned, even banks).
#define WT_S 264

__global__ __launch_bounds__(256, 2) void gemm_kernel(
        const float* __restrict__ x1, const float* __restrict__ x2,
        const unsigned short* __restrict__ wT,     // [N_H][N_IN] bf16 bits
        unsigned short* __restrict__ hb) {         // [M_TOT][N_H] bf16 bits
    __shared__ unsigned short wl[N_H * WT_S];      // 66 KB -> 2 blocks/CU
    const int t = threadIdx.x;
#pragma unroll
    for (int i = 0; i < 16; ++i) {                 // 4096 x 16B, coalesced
        int f  = t + i * 256;
        int n  = f >> 5;
        int kp = (f & 31) * 8;
        *(u16x8*)(wl + n * WT_S + kp) = *(const u16x8*)(wT + n * N_IN + kp);
    }
    __syncthreads();

    const int wave = t >> 6, lane = t & 63;
    const int quad = lane >> 4, l16 = lane & 15;
    const int mw = blockIdx.x * 64 + wave * 16;    // wave's base output row
    const float* x = (mw < N_NODES) ? x1 : x2;
    const int mrow = (mw < N_NODES) ? mw : mw - N_NODES;

    fx4 acc[8];
#pragma unroll
    for (int c = 0; c < 8; ++c) acc[c] = (fx4){0.f, 0.f, 0.f, 0.f};

    // A-frag: A[m=l16][k=quad*8+j] -> lane reads 32B of its row, converts to bf16
    const float* xrow = x + (size_t)(mrow + l16) * N_IN;
#pragma unroll
    for (int kk = 0; kk < N_IN; kk += 32) {
        float4 a0 = *(const float4*)(xrow + kk + quad * 8);
        float4 a1 = *(const float4*)(xrow + kk + quad * 8 + 4);
        u16x8 au;
        au[0] = f2bf(a0.x); au[1] = f2bf(a0.y); au[2] = f2bf(a0.z); au[3] = f2bf(a0.w);
        au[4] = f2bf(a1.x); au[5] = f2bf(a1.y); au[6] = f2bf(a1.z); au[7] = f2bf(a1.w);
        bfx8 af = __builtin_bit_cast(bfx8, au);
#pragma unroll
        for (int c = 0; c < 8; ++c) {
            // B-frag: B[n=c*16+l16][k=quad*8+j] from LDS (2-way banks = free)
            bfx8 bf = *(const bfx8*)(wl + (size_t)(c * 16 + l16) * WT_S + kk + quad * 8);
            acc[c] = __builtin_amdgcn_mfma_f32_16x16x32_bf16(af, bf, acc[c], 0, 0, 0);
        }
    }
    // C/D: col = l16, row = quad*4 + reg  (verified gfx950 mapping)
#pragma unroll
    for (int c = 0; c < 8; ++c)
#pragma unroll
        for (int r = 0; r < 4; ++r)
            hb[(size_t)(mw + quad * 4 + r) * N_H + c * 16 + l16] = f2bf(acc[c][r]);
}

// ---------------- CSR build: histogram -> scan -> scatter --------------------
__global__ __launch_bounds__(256) void hist_kernel(const int* __restrict__ ei,
                                                   int* __restrict__ deg) {
    int e = blockIdx.x * 256 + threadIdx.x;
    if (e < N_EDGES) atomicAdd(deg + ei[e], 1);
}

__global__ __launch_bounds__(256) void scan1_kernel(const int* __restrict__ deg,
                                                    int* __restrict__ part,
                                                    int* __restrict__ bsum) {
    __shared__ int s[256];
    int g = blockIdx.x * 256 + threadIdx.x;
    int v = (g < N_NODES) ? deg[g] : 0;
    s[threadIdx.x] = v;
    __syncthreads();
#pragma unroll
    for (int off = 1; off < 256; off <<= 1) {
        int t = (threadIdx.x >= off) ? s[threadIdx.x - off] : 0;
        __syncthreads();
        s[threadIdx.x] += t;
        __syncthreads();
    }
    if (g < N_NODES) part[g] = s[threadIdx.x] - v;
    if (threadIdx.x == 255) bsum[blockIdx.x] = s[255];
}

#define NBLK_SCAN 391
__global__ void scan2_kernel(int* __restrict__ bsum) {
    __shared__ int s[512];
    int v = (threadIdx.x < NBLK_SCAN) ? bsum[threadIdx.x] : 0;
    s[threadIdx.x] = v;
    __syncthreads();
#pragma unroll
    for (int off = 1; off < 512; off <<= 1) {
        int t = (threadIdx.x >= off) ? s[threadIdx.x - off] : 0;
        __syncthreads();
        s[threadIdx.x] += t;
        __syncthreads();
    }
    if (threadIdx.x < NBLK_SCAN) bsum[threadIdx.x] = s[threadIdx.x] - v;
}

__global__ __launch_bounds__(256) void scan3_kernel(const int* __restrict__ part,
                                                    const int* __restrict__ bsum,
                                                    int* __restrict__ off,
                                                    int* __restrict__ cursor) {
    int g = blockIdx.x * 256 + threadIdx.x;
    if (g < N_NODES) {
        int o = part[g] + bsum[blockIdx.x];
        off[g] = o;
        cursor[g] = o;
    }
    if (g == 0) off[N_NODES] = N_EDGES;
}

__global__ __launch_bounds__(256) void scatter_kernel(const int* __restrict__ ei,
                                                      const float* __restrict__ ew,
                                                      int* __restrict__ cursor,
                                                      int2* __restrict__ edata) {
    int e = blockIdx.x * 256 + threadIdx.x;
    if (e >= N_EDGES) return;
    int row = ei[e];
    int pos = atomicAdd(cursor + row, 1);
    edata[pos] = make_int2(ei[N_EDGES + e], __float_as_int(ew[e]));
}

// ------- fused segment-sum SPMM + bias + PReLU + wsum-dot, both branches ----
// one wave per node; lane covers features (2*lane, 2*lane+1): ushort2 = 4B/lane,
// full wave gathers one 256B h-row per edge. No atomics.
__global__ __launch_bounds__(256) void gcn_seg_kernel(const int* __restrict__ off,
                                                      const int2* __restrict__ edata,
                                                      const unsigned short* __restrict__ hb,
                                                      const float* __restrict__ gcn_bias,
                                                      const float* __restrict__ prelu_a,
                                                      const float* __restrict__ wsum,
                                                      float* __restrict__ zout) {
    const int wave = threadIdx.x >> 6, lane = threadIdx.x & 63;
    const int node = blockIdx.x * 4 + wave;        // 0..199999
    const unsigned short* h = hb;
    float* z = zout;
    int n = node;
    if (node >= N_NODES) { h += (size_t)N_NODES * N_H; z += N_NODES; n -= N_NODES; }
    const int s = off[n], e = off[n + 1];
    float a0 = 0.f, a1 = 0.f;
    int i = s;
    for (; i + 1 < e; i += 2) {
        int2 e0 = edata[i], e1 = edata[i + 1];
        float w0 = __int_as_float(e0.y), w1 = __int_as_float(e1.y);
        ushort2 h0 = *(const ushort2*)(h + (size_t)e0.x * N_H + lane * 2);
        ushort2 h1 = *(const ushort2*)(h + (size_t)e1.x * N_H + lane * 2);
        a0 += w0 * bf2f(h0.x) + w1 * bf2f(h1.x);
        a1 += w0 * bf2f(h0.y) + w1 * bf2f(h1.y);
    }
    if (i < e) {
        int2 e0 = edata[i];
        float w0 = __int_as_float(e0.y);
        ushort2 h0 = *(const ushort2*)(h + (size_t)e0.x * N_H + lane * 2);
        a0 += w0 * bf2f(h0.x);
        a1 += w0 * bf2f(h0.y);
    }
    const float alpha = prelu_a[0];
    float v0 = a0 + gcn_bias[2 * lane];
    float v1 = a1 + gcn_bias[2 * lane + 1];
    v0 = (v0 >= 0.f) ? v0 : alpha * v0;
    v1 = (v1 >= 0.f) ? v1 : alpha * v1;
    float sres = v0 * wsum[2 * lane] + v1 * wsum[2 * lane + 1];
#pragma unroll
    for (int o = 32; o; o >>= 1) sres += __shfl_down(sres, o, 64);
    if (lane == 0) z[n] = sres + wsum[128];        // wsum[128] = b_sum
}

// -------- prep: W^T in bf16 (block 0) + w_sum/b_sum (block 1) ---------------
__global__ void wprep_kernel(const float* __restrict__ W,
                             const float* __restrict__ linW,
                             const float* __restrict__ linb,
                             unsigned short* __restrict__ wT,
                             float* __restrict__ wsum) {
    if (blockIdx.x == 0) {
        int t = threadIdx.x;
        for (int i = 0; i < (N_IN * N_H) / 256; ++i) {
            int o = i * 256 + t;          // o = n*256 + k
            int n = o >> 8, k = o & 255;
            wT[o] = f2bf(W[(size_t)k * N_H + n]);
        }
    } else {
        int j = threadIdx.x;
        if (j < N_H) {
            float s = 0.f;
            for (int o = 0; o < N_H; ++o) s += linW[j * N_H + o];
            wsum[j] = s;
        }
        if (j == N_H) {
            float s = 0.f;
            for (int o = 0; o < N_H; ++o) s += linb[o];
            wsum[N_H] = s;
        }
    }
}

extern "C" void kernel_launch(void* const* d_in, const int* in_sizes, int n_in,
                              void* d_out, int out_size, void* d_ws, size_t ws_size,
                              hipStream_t stream) {
    const float* x1 = (const float*)d_in[0];
    const float* x2 = (const float*)d_in[1];
    const int*   ei = (const int*)d_in[2];
    const float* ew = (const float*)d_in[3];
    const float* Wg = (const float*)d_in[4];
    const float* gb = (const float*)d_in[5];
    const float* pa = (const float*)d_in[6];
    const float* lW = (const float*)d_in[7];
    const float* lb = (const float*)d_in[8];
    float* zout = (float*)d_out;

    // ws layout
    unsigned short* hb   = (unsigned short*)d_ws;          // 25,600,000 u16 (51.2MB)
    int2*  edata  = (int2*)(hb + (size_t)M_TOT * N_H);     //    800,000 int2 (6.4MB)
    unsigned short* wT   = (unsigned short*)(edata + N_EDGES);  // 32,768 u16
    int*   deg    = (int*)(wT + N_IN * N_H);               // 100,096 i
    int*   part   = deg + 100096;
    int*   off    = part + 100096;                          // uses 100001
    int*   cursor = off + 100096;
    int*   bsum   = cursor + 100096;                        // 512 i
    float* wsum   = (float*)(bsum + 512);                   // 129 f

    wprep_kernel<<<2, 256, 0, stream>>>(Wg, lW, lb, wT, wsum);

    hipMemsetAsync(deg, 0, (size_t)N_NODES * sizeof(int), stream);
    hist_kernel<<<(N_EDGES + 255) / 256, 256, 0, stream>>>(ei, deg);
    scan1_kernel<<<NBLK_SCAN, 256, 0, stream>>>(deg, part, bsum);
    scan2_kernel<<<1, 512, 0, stream>>>(bsum);
    scan3_kernel<<<NBLK_SCAN, 256, 0, stream>>>(part, bsum, off, cursor);
    scatter_kernel<<<(N_EDGES + 255) / 256, 256, 0, stream>>>(ei, ew, cursor, edata);

    gemm_kernel<<<M_TOT / 64, 256, 0, stream>>>(x1, x2, wT, hb);          // 3125
    gcn_seg_kernel<<<M_TOT / 4, 256, 0, stream>>>(off, edata, hb, gb, pa, wsum, zout);  // 50000
}

// Round 4
// 392.296 us; speedup vs baseline: 7.8514x; 1.1909x over previous
//
#include <hip/hip_runtime.h>

#define N_NODES 100000
#define N_EDGES 800000
#define N_IN    256
#define N_H     128
#define M_TOT   (2 * N_NODES)   // 200000; 16 | 100000 so waves never straddle branches

typedef __bf16 bfx8 __attribute__((ext_vector_type(8)));
typedef unsigned short u16x8 __attribute__((ext_vector_type(8)));
typedef float fx4 __attribute__((ext_vector_type(4)));

__device__ inline unsigned short f2bf(float f) {
    union { float f; unsigned u; } v; v.f = f;
    return (unsigned short)((v.u + 0x7FFF + ((v.u >> 16) & 1)) >> 16);  // RNE
}
__device__ inline float bf2f(unsigned short s) {
    union { unsigned u; float f; } v; v.u = ((unsigned)s) << 16;
    return v.f;
}

// ---------------- fused bf16-MFMA GEMM (both branches) + edge scatter --------
// Blocks [0, NGB): GEMM, 512 threads = 8 waves x 16 rows = 128 rows/block.
// Blocks [NGB, NGB+NSB): scatter edges into CSR slots (overlaps with GEMM).
#define WT_S 264
#define NGB  1563   // ceil(200000/128)
#define NSB  1563   // ceil(800000/512)

__global__ __launch_bounds__(512, 2) void gemm_scatter_kernel(
        const float* __restrict__ x1, const float* __restrict__ x2,
        const unsigned short* __restrict__ wT,     // [N_H][N_IN] bf16 bits
        unsigned short* __restrict__ hb,           // [M_TOT][N_H] bf16 bits
        const int* __restrict__ ei, const float* __restrict__ ew,
        int* __restrict__ cursor, int2* __restrict__ edata) {
    const int t = threadIdx.x;
    if (blockIdx.x >= NGB) {                       // ---- scatter part ----
        int e = (blockIdx.x - NGB) * 512 + t;
        if (e < N_EDGES) {
            int row = ei[e];
            int pos = atomicAdd(cursor + row, 1);
            edata[pos] = make_int2(ei[N_EDGES + e] * N_H, __float_as_int(ew[e]));
        }
        return;
    }
    // ---- GEMM part ----
    __shared__ unsigned short wl[N_H * WT_S];      // 66 KB -> 2 blocks/CU, 16 waves/CU
#pragma unroll
    for (int i = 0; i < 8; ++i) {                  // 4096 x 16B, coalesced
        int f  = t + i * 512;
        int n  = f >> 5;
        int kp = (f & 31) * 8;
        *(u16x8*)(wl + n * WT_S + kp) = *(const u16x8*)(wT + n * N_IN + kp);
    }
    __syncthreads();

    const int wave = t >> 6, lane = t & 63;
    const int quad = lane >> 4, l16 = lane & 15;
    const int mw = blockIdx.x * 128 + wave * 16;   // wave's base output row
    if (mw >= M_TOT) return;                       // tail waves of last block
    const float* x = (mw < N_NODES) ? x1 : x2;
    const int mrow = (mw < N_NODES) ? mw : mw - N_NODES;

    fx4 acc[8];
#pragma unroll
    for (int c = 0; c < 8; ++c) acc[c] = (fx4){0.f, 0.f, 0.f, 0.f};

    const float* xrow = x + (size_t)(mrow + l16) * N_IN;
#pragma unroll
    for (int kk = 0; kk < N_IN; kk += 32) {
        float4 a0 = *(const float4*)(xrow + kk + quad * 8);
        float4 a1 = *(const float4*)(xrow + kk + quad * 8 + 4);
        u16x8 au;
        au[0] = f2bf(a0.x); au[1] = f2bf(a0.y); au[2] = f2bf(a0.z); au[3] = f2bf(a0.w);
        au[4] = f2bf(a1.x); au[5] = f2bf(a1.y); au[6] = f2bf(a1.z); au[7] = f2bf(a1.w);
        bfx8 af = __builtin_bit_cast(bfx8, au);
#pragma unroll
        for (int c = 0; c < 8; ++c) {
            bfx8 bf = *(const bfx8*)(wl + (size_t)(c * 16 + l16) * WT_S + kk + quad * 8);
            acc[c] = __builtin_amdgcn_mfma_f32_16x16x32_bf16(af, bf, acc[c], 0, 0, 0);
        }
    }
    // C/D: col = l16, row = quad*4 + reg
#pragma unroll
    for (int c = 0; c < 8; ++c)
#pragma unroll
        for (int r = 0; r < 4; ++r)
            hb[(size_t)(mw + quad * 4 + r) * N_H + c * 16 + l16] = f2bf(acc[c][r]);
}

// ------- prep: histogram (blocks 0..3124) + W^T bf16 (32 blks) + wsum (1) ----
#define HIST_BLKS 3125   // ceil(800000/256)
__global__ __launch_bounds__(256) void prep_kernel(const int* __restrict__ ei,
                                                   int* __restrict__ deg,
                                                   const float* __restrict__ W,
                                                   unsigned short* __restrict__ wT,
                                                   const float* __restrict__ linW,
                                                   const float* __restrict__ linb,
                                                   float* __restrict__ wsum) {
    const int t = threadIdx.x;
    if (blockIdx.x < HIST_BLKS) {
        int e = blockIdx.x * 256 + t;
        if (e < N_EDGES) atomicAdd(deg + ei[e], 1);
    } else if (blockIdx.x < HIST_BLKS + 32) {
        int kb = (blockIdx.x - HIST_BLKS) * 8;     // 8 k-rows per block
#pragma unroll
        for (int p = 0; p < 4; ++p) {
            int idx = p * 256 + t;                 // 0..1023
            int k = kb + (idx >> 7), n = idx & 127;
            wT[(size_t)n * N_IN + k] = f2bf(W[(size_t)k * N_H + n]);  // coalesced read
        }
    } else {
        int j = t;
        if (j < N_H) {
            float s = 0.f;
            for (int o = 0; o < N_H; ++o) s += linW[j * N_H + o];
            wsum[j] = s;
        }
        if (j == N_H) {
            float s = 0.f;
            for (int o = 0; o < N_H; ++o) s += linb[o];
            wsum[N_H] = s;
        }
    }
}

// ---------------- scans ------------------------------------------------------
__global__ __launch_bounds__(256) void scan1_kernel(const int* __restrict__ deg,
                                                    int* __restrict__ part,
                                                    int* __restrict__ bsum) {
    __shared__ int s[256];
    int g = blockIdx.x * 256 + threadIdx.x;
    int v = (g < N_NODES) ? deg[g] : 0;
    s[threadIdx.x] = v;
    __syncthreads();
#pragma unroll
    for (int off = 1; off < 256; off <<= 1) {
        int t = (threadIdx.x >= off) ? s[threadIdx.x - off] : 0;
        __syncthreads();
        s[threadIdx.x] += t;
        __syncthreads();
    }
    if (g < N_NODES) part[g] = s[threadIdx.x] - v;
    if (threadIdx.x == 255) bsum[blockIdx.x] = s[255];
}

#define NBLK_SCAN 391
__global__ void scan2_kernel(int* __restrict__ bsum) {
    __shared__ int s[512];
    int v = (threadIdx.x < NBLK_SCAN) ? bsum[threadIdx.x] : 0;
    s[threadIdx.x] = v;
    __syncthreads();
#pragma unroll
    for (int off = 1; off < 512; off <<= 1) {
        int t = (threadIdx.x >= off) ? s[threadIdx.x - off] : 0;
        __syncthreads();
        s[threadIdx.x] += t;
        __syncthreads();
    }
    if (threadIdx.x < NBLK_SCAN) bsum[threadIdx.x] = s[threadIdx.x] - v;
}

__global__ __launch_bounds__(256) void scan3_kernel(const int* __restrict__ part,
                                                    const int* __restrict__ bsum,
                                                    int* __restrict__ off,
                                                    int* __restrict__ cursor) {
    int g = blockIdx.x * 256 + threadIdx.x;
    if (g < N_NODES) {
        int o = part[g] + bsum[blockIdx.x];
        off[g] = o;
        cursor[g] = o;
    }
    if (g == 0) off[N_NODES] = N_EDGES;
}

// ------- fused segment-sum SPMM + bias + PReLU + wsum-dot, BOTH branches -----
// one wave per node, lane covers features (2*lane, 2*lane+1); per edge it
// gathers the h1-row AND h2-row (edata read once, 4 loads in flight w/ unroll2)
__global__ __launch_bounds__(256) void gcn_seg_kernel(const int* __restrict__ off,
                                                      const int2* __restrict__ edata,
                                                      const unsigned short* __restrict__ hb,
                                                      const float* __restrict__ gcn_bias,
                                                      const float* __restrict__ prelu_a,
                                                      const float* __restrict__ wsum,
                                                      float* __restrict__ zout) {
    const int wave = threadIdx.x >> 6, lane = threadIdx.x & 63;
    const int node = blockIdx.x * 4 + wave;        // 0..99999 (grid 25000)
    const unsigned short* h1 = hb;
    const unsigned short* h2 = hb + (size_t)N_NODES * N_H;
    const int s = __builtin_amdgcn_readfirstlane(off[node]);
    const int e = __builtin_amdgcn_readfirstlane(off[node + 1]);
    const int l2 = lane * 2;
    float a0 = 0.f, a1 = 0.f;                      // branch 1 accum
    float b0 = 0.f, b1 = 0.f;                      // branch 2 accum
    int i = s;
    for (; i + 1 < e; i += 2) {
        int2 E0 = edata[i], E1 = edata[i + 1];     // E.x = col*N_H
        float w0 = __int_as_float(E0.y), w1 = __int_as_float(E1.y);
        ushort2 p10 = *(const ushort2*)(h1 + E0.x + l2);
        ushort2 p20 = *(const ushort2*)(h2 + E0.x + l2);
        ushort2 p11 = *(const ushort2*)(h1 + E1.x + l2);
        ushort2 p21 = *(const ushort2*)(h2 + E1.x + l2);
        a0 += w0 * bf2f(p10.x) + w1 * bf2f(p11.x);
        a1 += w0 * bf2f(p10.y) + w1 * bf2f(p11.y);
        b0 += w0 * bf2f(p20.x) + w1 * bf2f(p21.x);
        b1 += w0 * bf2f(p20.y) + w1 * bf2f(p21.y);
    }
    if (i < e) {
        int2 E0 = edata[i];
        float w0 = __int_as_float(E0.y);
        ushort2 p10 = *(const ushort2*)(h1 + E0.x + l2);
        ushort2 p20 = *(const ushort2*)(h2 + E0.x + l2);
        a0 += w0 * bf2f(p10.x);
        a1 += w0 * bf2f(p10.y);
        b0 += w0 * bf2f(p20.x);
        b1 += w0 * bf2f(p20.y);
    }
    const float alpha = prelu_a[0];
    const float g0 = gcn_bias[l2], g1 = gcn_bias[l2 + 1];
    const float q0 = wsum[l2],     q1 = wsum[l2 + 1];
    float v0 = a0 + g0, v1 = a1 + g1;
    float u0 = b0 + g0, u1 = b1 + g1;
    v0 = (v0 >= 0.f) ? v0 : alpha * v0;
    v1 = (v1 >= 0.f) ? v1 : alpha * v1;
    u0 = (u0 >= 0.f) ? u0 : alpha * u0;
    u1 = (u1 >= 0.f) ? u1 : alpha * u1;
    float s1 = v0 * q0 + v1 * q1;
    float s2 = u0 * q0 + u1 * q1;
#pragma unroll
    for (int o = 32; o; o >>= 1) {
        s1 += __shfl_down(s1, o, 64);
        s2 += __shfl_down(s2, o, 64);
    }
    if (lane == 0) {
        zout[node]           = s1 + wsum[128];     // wsum[128] = b_sum
        zout[node + N_NODES] = s2 + wsum[128];
    }
}

extern "C" void kernel_launch(void* const* d_in, const int* in_sizes, int n_in,
                              void* d_out, int out_size, void* d_ws, size_t ws_size,
                              hipStream_t stream) {
    const float* x1 = (const float*)d_in[0];
    const float* x2 = (const float*)d_in[1];
    const int*   ei = (const int*)d_in[2];
    const float* ew = (const float*)d_in[3];
    const float* Wg = (const float*)d_in[4];
    const float* gb = (const float*)d_in[5];
    const float* pa = (const float*)d_in[6];
    const float* lW = (const float*)d_in[7];
    const float* lb = (const float*)d_in[8];
    float* zout = (float*)d_out;

    unsigned short* hb   = (unsigned short*)d_ws;               // 25.6M u16
    int2*  edata  = (int2*)(hb + (size_t)M_TOT * N_H);          // 800k int2
    unsigned short* wT   = (unsigned short*)(edata + N_EDGES);  // 32768 u16
    int*   deg    = (int*)(wT + N_IN * N_H);                    // 100096 i
    int*   part   = deg + 100096;
    int*   off    = part + 100096;                              // uses 100001
    int*   cursor = off + 100096;
    int*   bsum   = cursor + 100096;                            // 512 i
    float* wsum   = (float*)(bsum + 512);                       // 129 f

    hipMemsetAsync(deg, 0, (size_t)N_NODES * sizeof(int), stream);
    prep_kernel<<<HIST_BLKS + 33, 256, 0, stream>>>(ei, deg, Wg, wT, lW, lb, wsum);
    scan1_kernel<<<NBLK_SCAN, 256, 0, stream>>>(deg, part, bsum);
    scan2_kernel<<<1, 512, 0, stream>>>(bsum);
    scan3_kernel<<<NBLK_SCAN, 256, 0, stream>>>(part, bsum, off, cursor);
    gemm_scatter_kernel<<<NGB + NSB, 512, 0, stream>>>(x1, x2, wT, hb,
                                                       ei, ew, cursor, edata);
    gcn_seg_kernel<<<N_NODES / 4, 256, 0, stream>>>(off, edata, hb, gb, pa, wsum, zout);
}